// Round 17
// baseline (31.485 us; speedup 1.0000x reference)
//
#include <hip/hip_runtime.h>
#include <math.h>

// y_t = clamp(y_{t-1}, x_t, x_t+1): play operator as associative clamp-scan.
// compose(l, r) = "apply l first, then r". min/max/med3-only => exact =>
// any regrouping is bit-identical (deterministic).
//
// COLLAPSE PROPERTY: composed windows contract and width-0 is absorbing.
// Element 0's window is (p0,p0), so ANY prefix reaching element 0 is
// collapsed. Each block recomputes its exact incoming value from the RAW
// INPUT halo (backward 256-element chunks until collapse; guaranteed at
// element 0). NO inter-block communication (rounds 2/10/11: cross-XCD sync
// through non-coherent L2s costs 2-6x, fenced or relaxed).
//
// GROUPS LAYOUT: tile = GPB groups x 1024; in group v, thread t owns
// elements tile0+1024v+4t..+3 -- one float4, lane-contiguous loads AND
// stores (1 KB/wave/instruction), no LDS transpose.
// GPB=8 (EPB=8192): rounds 12/15/16 showed access-pattern changes are
// noise-level; the remaining lever is per-block fixed cost (halo-walk
// latency bubble, block scan) -- halve the block count.

#define TPB 256
#define GPB 8                 // groups per block
#define GSZ (TPB * 4)         // 1024 elements per group
#define EPB (GPB * GSZ)       // 8192 per block -> nb = 2049 for T=2^24
#define NW  (TPB / 64)
#define HCH 256               // halo chunk: 1 element per thread

struct Pair { float a, b; };

__device__ __forceinline__ float med3f(float x, float lo, float hi) {
    return __builtin_amdgcn_fmed3f(x, lo, hi);   // clamp(x, lo, hi), lo<=hi
}
__device__ __forceinline__ Pair compose(Pair l, Pair r) {
    Pair o; o.a = med3f(l.a, r.a, r.b); o.b = med3f(l.b, r.a, r.b); return o;
}
__device__ __forceinline__ Pair ident() {
    Pair p; p.a = -INFINITY; p.b = INFINITY; return p;
}

__global__ __launch_bounds__(TPB)
void k_scan(const float* __restrict__ in, const float* __restrict__ kptr,
            float* __restrict__ out, int n) {
    const int tid  = threadIdx.x, lane = tid & 63, wid = tid >> 6;
    const int vid  = blockIdx.x;
    const int tile0 = vid * EPB;
    const float k   = kptr[0];
    const bool blockFull = (tile0 + EPB <= n);   // uniform across block

    __shared__ Pair wS[GPB][NW];   // per-group wave aggregates (256 B)
    __shared__ Pair wC[NW];        // halo-chunk wave aggregates

    // ---- 0) prefetch first halo chunk (latency hides under tile phase) ----
    float hx = 0.0f;
    if (tile0 > 0) hx = in[tile0 - HCH + tid];

    // ---- 1) per-group: lane-contiguous load, thread windows, wave scan ----
    float ta[GPB][4], tb[GPB][4];                // static indexing only
    Pair  upv[GPB];                              // shfl_up(w,1) per group
    #pragma unroll
    for (int v = 0; v < GPB; ++v) {
        const int b4 = tile0 + v * GSZ + 4 * tid;
        float xv[4];
        if (blockFull) {
            float4 f = reinterpret_cast<const float4*>(in + tile0 + v * GSZ)[tid];
            xv[0] = f.x; xv[1] = f.y; xv[2] = f.z; xv[3] = f.w;
        } else {
            #pragma unroll
            for (int j = 0; j < 4; ++j)
                xv[j] = (b4 + j < n) ? in[b4 + j] : 0.0f;
        }
        float a = -INFINITY, b = INFINITY;
        #pragma unroll
        for (int j = 0; j < 4; ++j) {
            if (blockFull || b4 + j < n) {
                float lo = xv[j] * k, hi = lo + 1.0f;
                if (j == 0 && b4 == 0) { lo = xv[0]; hi = xv[0]; }  // const p0
                a = med3f(a, lo, hi);
                b = med3f(b, lo, hi);
            }
            ta[v][j] = a; tb[v][j] = b;
        }
        Pair w; w.a = a; w.b = b;
        #pragma unroll
        for (int off = 1; off < 64; off <<= 1) {
            Pair u; u.a = __shfl_up(w.a, off); u.b = __shfl_up(w.b, off);
            if (lane >= off) w = compose(u, w);
        }
        upv[v].a = __shfl_up(w.a, 1); upv[v].b = __shfl_up(w.b, 1);
        if (lane == 63) wS[v][wid] = w;
    }
    __syncthreads();                             // one barrier for all scans

    // ---- 2) halo backward walk: exact incoming value, no communication ----
    Pair S = ident();
    int chunkEnd = tile0;
    bool first = true;
    while (chunkEnd > 0) {
        const int chunkStart = chunkEnd - HCH;   // tile0 % HCH == 0
        const int e = chunkStart + tid;
        float x = first ? hx : in[e];
        first = false;
        Pair wnd;
        {
            float lo = x * k, hi = lo + 1.0f;
            if (e == 0) { lo = x; hi = x; }      // constant p0
            wnd.a = lo; wnd.b = hi;
        }
        // ordered wave tree-reduce; lane 0 = ascending-order wave aggregate
        #pragma unroll
        for (int off = 1; off < 64; off <<= 1) {
            Pair u; u.a = __shfl_down(wnd.a, off); u.b = __shfl_down(wnd.b, off);
            Pair c = compose(wnd, u);
            if (lane + off < 64) wnd = c;
        }
        if (lane == 0) wC[wid] = wnd;
        __syncthreads();
        Pair cagg = wC[0];
        #pragma unroll
        for (int i = 1; i < NW; ++i) cagg = compose(cagg, wC[i]);
        __syncthreads();                         // protect wC for next iter
        S = compose(cagg, S);                    // prepend older chunk
        if (S.a == S.b) break;                   // collapsed: exact
        chunkEnd = chunkStart;
    }
    float y = med3f(0.0f, S.a, S.b);             // vid 0: med3(0,-inf,inf)=0

    // ---- 3) per-group apply + chain: lane-contiguous float4 stores --------
    #pragma unroll
    for (int v = 0; v < GPB; ++v) {
        Pair wpre = ident();
        #pragma unroll
        for (int i = 0; i < NW; ++i) if (i < wid) wpre = compose(wpre, wS[v][i]);
        Pair ex = (lane == 0) ? wpre : compose(wpre, upv[v]);
        const float ytin = med3f(y, ex.a, ex.b); // exact incoming value
        // chain y across groups via the group aggregate
        Pair G = wS[v][0];
        #pragma unroll
        for (int i = 1; i < NW; ++i) G = compose(G, wS[v][i]);
        y = med3f(y, G.a, G.b);

        const int b4 = tile0 + v * GSZ + 4 * tid;
        if (blockFull) {
            float4 o;
            o.x = med3f(ytin, ta[v][0], tb[v][0]);
            o.y = med3f(ytin, ta[v][1], tb[v][1]);
            o.z = med3f(ytin, ta[v][2], tb[v][2]);
            o.w = med3f(ytin, ta[v][3], tb[v][3]);
            reinterpret_cast<float4*>(out + tile0 + v * GSZ)[tid] = o;
        } else {
            #pragma unroll
            for (int j = 0; j < 4; ++j)
                if (b4 + j < n) out[b4 + j] = med3f(ytin, ta[v][j], tb[v][j]);
        }
    }
}

// ========================== host launcher ==================================
extern "C" void kernel_launch(void* const* d_in, const int* in_sizes, int n_in,
                              void* d_out, int out_size, void* d_ws, size_t ws_size,
                              hipStream_t stream) {
    const float* in   = (const float*)d_in[0];   // [T+1], in[0] = p0
    const float* kptr = (const float*)d_in[1];   // scalar weight
    float* out = (float*)d_out;                  // [T+1]
    const int n  = in_sizes[0];
    const int nb = (n + EPB - 1) / EPB;          // 2049 for T = 2^24

    k_scan<<<nb, TPB, 0, stream>>>(in, kptr, out, n);
}

// Round 18
// 26.026 us; speedup vs baseline: 1.2097x; 1.2097x over previous
//
#include <hip/hip_runtime.h>
#include <math.h>

// y_t = clamp(y_{t-1}, x_t, x_t+1): play operator as associative clamp-scan.
// compose(l, r) = "apply l first, then r". min/max/med3-only => exact =>
// any regrouping is bit-identical (deterministic).
//
// COLLAPSE PROPERTY (two levels):
//  - block level: each block recomputes its exact incoming value from the
//    RAW INPUT halo (backward 256-elem chunks until the suffix composition
//    collapses to width 0; guaranteed at element 0 = constant p0). No
//    inter-block communication (rounds 2/10/11: cross-XCD sync costs 2-6x).
//  - thread level (NEW): a thread's incoming value = predecessor thread's
//    16-element aggregate's constant whenever that aggregate is width-0
//    (~always for this data). Replaces the 12-shuffle Hillis-Steele block
//    scan with ONE shfl_up; block-uniform ballot falls back to the full
//    scan when any predecessor window is still open (exact either way).
//    Rationale: R15 (1 scan) beat R16 (4 scans) -- DS-pipe op count is the
//    marginal cost; this removes most of it.

#define TPB 256
#define EPT 16
#define EPB (TPB * EPT)   // 4096 per block -> nb = 4097 for T=2^24
#define NW  (TPB / 64)
#define HCH 256           // halo chunk: 1 element per thread

struct Pair { float a, b; };

__device__ __forceinline__ float med3f(float x, float lo, float hi) {
    return __builtin_amdgcn_fmed3f(x, lo, hi);   // clamp(x, lo, hi), lo<=hi
}
__device__ __forceinline__ Pair compose(Pair l, Pair r) {
    Pair o; o.a = med3f(l.a, r.a, r.b); o.b = med3f(l.b, r.a, r.b); return o;
}
__device__ __forceinline__ Pair ident() {
    Pair p; p.a = -INFINITY; p.b = INFINITY; return p;
}

__global__ __launch_bounds__(TPB)
void k_scan(const float* __restrict__ in, const float* __restrict__ kptr,
            float* __restrict__ out, int n) {
    const int tid  = threadIdx.x, lane = tid & 63, wid = tid >> 6;
    const int vid  = blockIdx.x;
    const int tile0 = vid * EPB;
    const int base  = tile0 + tid * EPT;
    const float k   = kptr[0];
    const bool blockFull = (tile0 + EPB <= n);   // uniform across block

    __shared__ float xpose[EPB];   // 16 KB transpose buffer
    __shared__ Pair  lastA[NW];    // lane-63 thread aggregates (fast path)
    __shared__ Pair  wS[NW];       // wave scan aggregates (slow path)
    __shared__ Pair  wC[NW];       // halo-chunk wave aggregates
    __shared__ int   sBad[NW];     // per-wave fallback flags

    // ---- 0) prefetch first halo chunk (latency hides under tile phase) ----
    float hx = 0.0f;
    if (tile0 > 0) hx = in[tile0 - HCH + tid];

    // ---- 1) tile load + per-element thread-local inclusive windows --------
    float ta[EPT], tb[EPT];                      // static indexing only
    {
        float a = -INFINITY, b = INFINITY;
        if (blockFull) {
            #pragma unroll
            for (int v = 0; v < EPT / 4; ++v) {
                float4 f = reinterpret_cast<const float4*>(in + base)[v];
                float xv[4] = {f.x, f.y, f.z, f.w};
                #pragma unroll
                for (int jj = 0; jj < 4; ++jj) {
                    float lo = xv[jj] * k, hi = lo + 1.0f;
                    if (v == 0 && jj == 0 && base == 0) { lo = xv[0]; hi = xv[0]; }
                    a = med3f(a, lo, hi);
                    b = med3f(b, lo, hi);
                    ta[4*v+jj] = a; tb[4*v+jj] = b;
                }
            }
        } else {
            #pragma unroll
            for (int j = 0; j < EPT; ++j) {
                if (base + j < n) {
                    float x = in[base + j];
                    float lo = x * k, hi = lo + 1.0f;
                    if (j == 0 && base == 0) { lo = x; hi = x; }
                    a = med3f(a, lo, hi);
                    b = med3f(b, lo, hi);
                }
                ta[j] = a; tb[j] = b;
            }
        }
    }
    Pair A; A.a = ta[EPT - 1]; A.b = tb[EPT - 1];    // thread aggregate
    if (lane == 63) lastA[wid] = A;
    __syncthreads();                                  // publish lastA

    // ---- 2) halo backward walk: exact incoming value, no communication ----
    Pair S = ident();
    {
        int chunkEnd = tile0;
        bool first = true;
        while (chunkEnd > 0) {
            const int cs = chunkEnd - HCH;           // tile0 % HCH == 0
            const int e  = cs + tid;
            float x = first ? hx : in[e];
            first = false;
            Pair wnd;
            {
                float lo = x * k, hi = lo + 1.0f;
                if (e == 0) { lo = x; hi = x; }      // constant p0
                wnd.a = lo; wnd.b = hi;
            }
            #pragma unroll
            for (int off = 1; off < 64; off <<= 1) {
                Pair u; u.a = __shfl_down(wnd.a, off); u.b = __shfl_down(wnd.b, off);
                Pair c = compose(wnd, u);
                if (lane + off < 64) wnd = c;
            }
            if (lane == 0) wC[wid] = wnd;
            __syncthreads();
            Pair cagg = wC[0];
            #pragma unroll
            for (int i = 1; i < NW; ++i) cagg = compose(cagg, wC[i]);
            __syncthreads();                         // protect wC next iter
            S = compose(cagg, S);                    // prepend older chunk
            if (S.a == S.b) break;                   // collapsed: exact
            chunkEnd = cs;
        }
    }
    const float y = med3f(0.0f, S.a, S.b);           // vid 0: 0, inert

    // ---- 3) per-thread incoming value: collapse fast path -----------------
    Pair prevA;
    prevA.a = __shfl_up(A.a, 1);
    prevA.b = __shfl_up(A.b, 1);
    if (lane == 0) {
        if (wid > 0) prevA = lastA[wid - 1];
        else { prevA.a = y; prevA.b = y; }           // tid 0: exact incoming
    }
    const bool bad = (prevA.a != prevA.b);           // predecessor still open
    const int wavebad = __any(bad) ? 1 : 0;
    if (lane == 0) sBad[wid] = wavebad;
    __syncthreads();
    int anybad = 0;
    #pragma unroll
    for (int i = 0; i < NW; ++i) anybad |= sBad[i];  // block-uniform

    float ytin;
    if (!anybad) {
        ytin = prevA.a;                              // width-0: exact value
    } else {
        // slow path (rare; always taken by the tail block): full block scan
        Pair w = A;
        #pragma unroll
        for (int off = 1; off < 64; off <<= 1) {
            Pair u; u.a = __shfl_up(w.a, off); u.b = __shfl_up(w.b, off);
            if (lane >= off) w = compose(u, w);
        }
        if (lane == 63) wS[wid] = w;
        __syncthreads();
        Pair wpre = ident();
        #pragma unroll
        for (int i = 0; i < NW; ++i) if (i < wid) wpre = compose(wpre, wS[i]);
        Pair up; up.a = __shfl_up(w.a, 1); up.b = __shfl_up(w.b, 1);
        Pair ex = (lane == 0) ? wpre : compose(wpre, up);
        ytin = med3f(y, ex.a, ex.b);
    }

    // ---- 4) apply + b128 swizzled transpose + coalesced store -------------
    if (blockFull) {
        #pragma unroll
        for (int v = 0; v < EPT / 4; ++v) {
            float4 ov;
            ov.x = med3f(ytin, ta[4*v+0], tb[4*v+0]);
            ov.y = med3f(ytin, ta[4*v+1], tb[4*v+1]);
            ov.z = med3f(ytin, ta[4*v+2], tb[4*v+2]);
            ov.w = med3f(ytin, ta[4*v+3], tb[4*v+3]);
            const unsigned u  = (unsigned)(tid * 4 + v);
            const unsigned us = u ^ ((u >> 3) & 7u);
            *reinterpret_cast<float4*>(&xpose[us * 4]) = ov;
        }
        __syncthreads();
        #pragma unroll
        for (int c4 = 0; c4 < EPT / 4; ++c4) {
            const unsigned u  = (unsigned)(c4 * TPB + tid);
            const unsigned us = u ^ ((u >> 3) & 7u);
            float4 f = *reinterpret_cast<const float4*>(&xpose[us * 4]);
            reinterpret_cast<float4*>(out + tile0)[u] = f;
        }
    } else {
        #pragma unroll
        for (int j = 0; j < EPT; ++j)
            if (base + j < n) out[base + j] = med3f(ytin, ta[j], tb[j]);
    }
}

// ========================== host launcher ==================================
extern "C" void kernel_launch(void* const* d_in, const int* in_sizes, int n_in,
                              void* d_out, int out_size, void* d_ws, size_t ws_size,
                              hipStream_t stream) {
    const float* in   = (const float*)d_in[0];   // [T+1], in[0] = p0
    const float* kptr = (const float*)d_in[1];   // scalar weight
    float* out = (float*)d_out;                  // [T+1]
    const int n  = in_sizes[0];
    const int nb = (n + EPB - 1) / EPB;          // 4097 for T = 2^24

    k_scan<<<nb, TPB, 0, stream>>>(in, kptr, out, n);
}